// Round 4
// baseline (242.107 us; speedup 1.0000x reference)
//
#include <hip/hip_runtime.h>
#include <math.h>

#define N_  2048
#define IN_ 400
#define C_  200
#define H_  256
#define M_  128
#define D_  8

#define KQ   224   // C_=200 padded to x32
#define KX   416   // IN_=400 padded to x32
#define KBIG 2176  // 2048 data + 8 bias + 120 pad (68*32, /4 K-splittable)
#define NZ   4     // K-split of big GEMM
#define KSPL (KBIG / NZ)   // 544 = 17*32

typedef __bf16 bf16x8 __attribute__((ext_vector_type(8)));
typedef float  f32x4  __attribute__((ext_vector_type(4)));

__device__ __forceinline__ ushort f2bf(float x) { __bf16 b = (__bf16)x; return __builtin_bit_cast(ushort, b); }
__device__ __forceinline__ float  bf2f(ushort u) { unsigned v = ((unsigned)u) << 16; return __builtin_bit_cast(float, v); }

// ---------------- prep_all: x_bf, q_bf, weight conversions, Wcat repack ----------------
// Region sizes (in ushort4 / 4-scalar units), all block-aligned:
#define P0 212992                  // x_bf: N * (KX/4)
#define P1 (P0 + 114688)           // q_bf: N * (KQ/4)
#define P2 (P1 + 81920)            // wconv: 327680/4 scalars-quads
#define P3 (P2 + 278528)           // Wcat: 512 * (KBIG/4)
// wconv scalar-region boundaries:
#define WC_KE (256 * KQ)                 // 57344
#define WC_VE (WC_KE + 256 * KX)         // 163840
#define WC_SW (WC_VE + 256 * 512)        // 294912
#define WC_KM (WC_SW + 128 * 256)        // 327680
__global__ __launch_bounds__(256) void prep_all_kernel(
    const float* __restrict__ x,
    const float* __restrict__ ke, const float* __restrict__ ve,
    const float* __restrict__ sw, const float* __restrict__ km,
    const float* __restrict__ er_w, const float* __restrict__ er_b,
    const float* __restrict__ ad_w, const float* __restrict__ ad_b,
    ushort* __restrict__ x_bf, ushort* __restrict__ q_bf,
    ushort* __restrict__ wout,   // ke|ve|sum|km contiguous
    ushort* __restrict__ wcat)
{
    int idx = blockIdx.x * 256 + threadIdx.x;
    ushort pk[4];
    if (idx < P0) {
        int n = idx / (KX / 4), g = idx % (KX / 4), c0 = g * 4;
#pragma unroll
        for (int j = 0; j < 4; j++) {
            int c = c0 + j;
            pk[j] = f2bf((c < IN_) ? x[(size_t)n * IN_ + c] : 0.f);
        }
        *(ushort4*)&x_bf[(size_t)n * KX + c0] = *(ushort4*)pk;
    } else if (idx < P1) {
        int i = idx - P0;
        int n = i / (KQ / 4), g = i % (KQ / 4), c0 = g * 4;
#pragma unroll
        for (int j = 0; j < 4; j++) {
            int c = c0 + j;
            pk[j] = f2bf((c < C_) ? x[(size_t)n * IN_ + c] + x[(size_t)n * IN_ + C_ + c] : 0.f);
        }
        *(ushort4*)&q_bf[(size_t)n * KQ + c0] = *(ushort4*)pk;
    } else if (idx < P2) {
        int s0 = (idx - P1) * 4;
#pragma unroll
        for (int j = 0; j < 4; j++) {
            int s = s0 + j;
            float val;
            if (s < WC_KE)      { int r = s / KQ, c = s % KQ; val = (c < C_) ? ke[r * C_ + c] : 0.f; }
            else if (s < WC_VE) { int i = s - WC_KE; int r = i / KX, c = i % KX; val = (c < IN_) ? ve[r * IN_ + c] : 0.f; }
            else if (s < WC_SW) { val = sw[s - WC_VE]; }
            else                { val = km[s - WC_SW]; }
            pk[j] = f2bf(val);
        }
        *(ushort4*)&wout[s0] = *(ushort4*)pk;
    } else {
        int i = idx - P2;
        int o = i / (KBIG / 4), g = i % (KBIG / 4), c0 = g * 4;
        const float* Wsrc = (o < 256) ? er_w : ad_w;
        const float* bsrc = (o < 256) ? er_b : ad_b;
        int oo = o & 255;
#pragma unroll
        for (int j = 0; j < 4; j++) {
            int c = c0 + j;
            float val = 0.f;
            if (c < 2048)      { int d = c >> 8, ii = c & 255; val = Wsrc[(size_t)(d * 256 + oo) * 256 + ii]; }
            else if (c < 2056) { val = bsrc[(c - 2048) * 256 + oo]; }
            pk[j] = f2bf(val);
        }
        *(ushort4*)&wcat[(size_t)o * KBIG + c0] = *(ushort4*)pk;
    }
}

// ---------------- unified bf16 MFMA NT GEMM ----------------
// C[m,n] = sum_k A[m,k]*B[n,k] (+bias[n]); tile 128x64, 4 waves (2x2),
// wave tile 64x32 -> 4x2 fragments of 16x16, BK=32. z splits K.
template<int OUTBF>
__global__ __launch_bounds__(256) void gemm_mfma(
    const ushort* __restrict__ A, int lda,
    const ushort* __restrict__ B, int ldb,
    const float* __restrict__ bias,
    void* __restrict__ Cv, int ldc, size_t csplit, int ksplit)
{
    constexpr int BM = 128, BN = 64;
    __shared__ ushort As[BM][40];
    __shared__ ushort Bs[BN][40];
    const int tid = threadIdx.x, lane = tid & 63, wave = tid >> 6;
    const int wm = (wave >> 1) * 64, wn = (wave & 1) * 32;
    const int m0 = blockIdx.y * BM, n0 = blockIdx.x * BN;
    const int kFrom = blockIdx.z * ksplit, kTo = kFrom + ksplit;

    f32x4 acc[4][2] = {};

    const int sr = tid >> 2;
    const int sc = (tid & 3) * 8;

    for (int k0 = kFrom; k0 < kTo; k0 += 32) {
        uint4 a0 = *(const uint4*)&A[(size_t)(m0 + sr) * lda + k0 + sc];
        uint4 a1 = *(const uint4*)&A[(size_t)(m0 + sr + 64) * lda + k0 + sc];
        uint4 b0 = *(const uint4*)&B[(size_t)(n0 + sr) * ldb + k0 + sc];
        *(uint4*)&As[sr][sc] = a0;
        *(uint4*)&As[sr + 64][sc] = a1;
        *(uint4*)&Bs[sr][sc] = b0;
        __syncthreads();

        const int ko = (lane >> 4) * 8;
        bf16x8 af[4], bfr[2];
#pragma unroll
        for (int i = 0; i < 4; i++)
            af[i] = __builtin_bit_cast(bf16x8, *(const uint4*)&As[wm + i * 16 + (lane & 15)][ko]);
#pragma unroll
        for (int j = 0; j < 2; j++)
            bfr[j] = __builtin_bit_cast(bf16x8, *(const uint4*)&Bs[wn + j * 16 + (lane & 15)][ko]);
#pragma unroll
        for (int i = 0; i < 4; i++)
#pragma unroll
            for (int j = 0; j < 2; j++)
                acc[i][j] = __builtin_amdgcn_mfma_f32_16x16x32_bf16(af[i], bfr[j], acc[i][j], 0, 0, 0);
        __syncthreads();
    }

    float* Cf = (float*)Cv + blockIdx.z * csplit;
    ushort* Cb = (ushort*)Cv;
#pragma unroll
    for (int i = 0; i < 4; i++) {
#pragma unroll
        for (int j = 0; j < 2; j++) {
            int row = m0 + wm + i * 16 + (lane >> 4) * 4;
            int col = n0 + wn + j * 16 + (lane & 15);
#pragma unroll
            for (int r = 0; r < 4; r++) {
                float val = acc[i][j][r];
                if (bias) val += bias[col];
                if (OUTBF) Cb[(size_t)(row + r) * ldc + col] = f2bf(val);
                else       Cf[(size_t)(row + r) * ldc + col] = val;
            }
        }
    }
}

// ---------------- vw: per-n w2 (dots + softmax D=8) then vw row fill ----------------
__global__ __launch_bounds__(256) void vw_kernel(
    const ushort* __restrict__ kbuf, const float* __restrict__ v,
    const float* __restrict__ kw2_w, const float* __restrict__ kw2_b,
    ushort* __restrict__ vw)
{
    __shared__ float kf[H_], vl[H_], lg[8], w2l[8];
    const int n = blockIdx.x, t = threadIdx.x;
    if (t < 64) {
        ushort4 u = ((const ushort4*)(kbuf + (size_t)n * H_))[t];
        kf[t * 4 + 0] = bf2f(u.x); kf[t * 4 + 1] = bf2f(u.y);
        kf[t * 4 + 2] = bf2f(u.z); kf[t * 4 + 3] = bf2f(u.w);
        float4 vv = ((const float4*)(v + (size_t)n * H_))[t];
        vl[t * 4 + 0] = vv.x; vl[t * 4 + 1] = vv.y;
        vl[t * 4 + 2] = vv.z; vl[t * 4 + 3] = vv.w;
    }
    __syncthreads();
    {
        int d = t >> 5, l = t & 31;
        float acc = 0.f;
        const float* wr = kw2_w + d * H_;
#pragma unroll
        for (int s = 0; s < 8; s++) acc += kf[l + 32 * s] * wr[l + 32 * s];
#pragma unroll
        for (int off = 16; off; off >>= 1) acc += __shfl_xor(acc, off);
        if (l == 0) lg[d] = acc + kw2_b[d];
    }
    __syncthreads();
    if (t < 8) {
        float val = lg[t];
        float mx = val;
#pragma unroll
        for (int off = 1; off < 8; off <<= 1) mx = fmaxf(mx, __shfl_xor(mx, off));
        float e = expf(val - mx), s = e;
#pragma unroll
        for (int off = 1; off < 8; off <<= 1) s += __shfl_xor(s, off);
        w2l[t] = e / s;
    }
    __syncthreads();
    ushort* row = vw + (size_t)n * KBIG;
    for (int g = t; g < KBIG / 4; g += 256) {
        int c0 = g * 4;
        ushort pk[4];
#pragma unroll
        for (int j = 0; j < 4; j++) {
            int c = c0 + j;
            float val = 0.f;
            if (c < 2048)      val = w2l[c >> 8] * vl[c & 255];
            else if (c < 2056) val = w2l[c - 2048];
            pk[j] = f2bf(val);
        }
        *(ushort4*)&row[c0] = *(ushort4*)pk;
    }
}

// ---------------- mega-fused memory pass ----------------
// per block n: w-logits(k.km)+softmax -> wl; e,a from parts; stream memory
// (r-reduce in LDS, erase/add write); f = tanh([k|r].sum_w+sum_b); y = f.out_w+out_b
__global__ __launch_bounds__(256) void mem_fused_kernel(
    const float* __restrict__ mem_in,
    const float* __restrict__ parts,       // NZ x N x 512
    const ushort* __restrict__ kbuf,       // N x 256 bf16
    const ushort* __restrict__ km_bf,      // 128 x 256
    const float* __restrict__ km_b,
    const ushort* __restrict__ sum_bf,     // 256 x 512
    const float* __restrict__ sum_b,
    const float* __restrict__ out_w, const float* __restrict__ out_b,
    float* __restrict__ mem_out, float* __restrict__ y)
{
    __shared__ float wl[M_];
    __shared__ float el[H_], al[H_], rl[H_];
    __shared__ ushort kl[H_];
    __shared__ float ypart[4];
    const int n = blockIdx.x, t = threadIdx.x;

    if (t < 64) ((ushort4*)kl)[t] = ((const ushort4*)(kbuf + (size_t)n * H_))[t];
    {
        const float* p = parts + (size_t)n * 512;
        float s0 = 0.f, s1 = 0.f;
#pragma unroll
        for (int z = 0; z < NZ; z++) {
            s0 += p[(size_t)z * N_ * 512 + t];
            s1 += p[(size_t)z * N_ * 512 + 256 + t];
        }
        el[t] = 1.f / (1.f + expf(-s0));
        al[t] = tanhf(s1);
    }
    __syncthreads();
    if (t < 128) {
        float acc = km_b[t];
        const uint4* kmr = (const uint4*)(km_bf + (size_t)t * H_);
        const uint4* klr = (const uint4*)kl;
#pragma unroll 4
        for (int g = 0; g < 32; g++) {
            uint4 a = klr[g], b = kmr[g];
            const ushort* au = (const ushort*)&a;
            const ushort* bu = (const ushort*)&b;
#pragma unroll
            for (int j = 0; j < 8; j++) acc += bf2f(au[j]) * bf2f(bu[j]);
        }
        wl[t] = acc;
    }
    __syncthreads();
    if (t < 64) {
        float v0 = wl[t], v1 = wl[t + 64];
        float mx = fmaxf(v0, v1);
#pragma unroll
        for (int off = 32; off; off >>= 1) mx = fmaxf(mx, __shfl_xor(mx, off));
        float e0 = expf(v0 - mx), e1 = expf(v1 - mx);
        float s = e0 + e1;
#pragma unroll
        for (int off = 32; off; off >>= 1) s += __shfl_xor(s, off);
        float inv = 1.f / s;
        wl[t] = e0 * inv;
        wl[t + 64] = e1 * inv;
    }
    __syncthreads();
    // streaming: 537 MB HBM phase
    {
        int wave = t >> 6, lane = t & 63, half = lane >> 5, l32 = lane & 31;
        const float4* min4 = (const float4*)(mem_in + (size_t)n * H_ * M_);
        float4* mout4 = (float4*)(mem_out + (size_t)n * H_ * M_);
        float4 wv = ((const float4*)wl)[l32];
        for (int h = wave * 2 + half; h < H_; h += 8) {
            float4 mv = min4[h * 32 + l32];
            float eh = el[h], ah = al[h];
            float4 nv;
            nv.x = mv.x * (1.f - wv.x * eh) + wv.x * ah;
            nv.y = mv.y * (1.f - wv.y * eh) + wv.y * ah;
            nv.z = mv.z * (1.f - wv.z * eh) + wv.z * ah;
            nv.w = mv.w * (1.f - wv.w * eh) + wv.w * ah;
            mout4[h * 32 + l32] = nv;
            float racc = mv.x * wv.x + mv.y * wv.y + mv.z * wv.z + mv.w * wv.w;
#pragma unroll
            for (int off = 1; off < 32; off <<= 1) racc += __shfl_xor(racc, off);
            if (l32 == 0) rl[h] = racc;
        }
    }
    __syncthreads();
    // f = tanh([k|r] . sum_w[t,:] + sum_b[t]); y = sum_h f_h*out_w[h] + out_b
    float facc = sum_b[t];
    const uint4* swr = (const uint4*)(sum_bf + (size_t)t * 512);
#pragma unroll 4
    for (int g = 0; g < 32; g++) {
        uint4 u = swr[g];
        const ushort* uu = (const ushort*)&u;
#pragma unroll
        for (int j = 0; j < 8; j++) facc += bf2f(kl[g * 8 + j]) * bf2f(uu[j]);
    }
#pragma unroll 4
    for (int g = 32; g < 64; g++) {
        uint4 u = swr[g];
        const ushort* uu = (const ushort*)&u;
        int base = g * 8 - 256;
#pragma unroll
        for (int j = 0; j < 8; j++) facc += rl[base + j] * bf2f(uu[j]);
    }
    float fh = tanhf(facc);
    float yv = fh * out_w[t];
#pragma unroll
    for (int off = 32; off; off >>= 1) yv += __shfl_xor(yv, off);
    if ((t & 63) == 0) ypart[t >> 6] = yv;
    __syncthreads();
    if (t == 0) y[n] = ypart[0] + ypart[1] + ypart[2] + ypart[3] + out_b[0];
}

extern "C" void kernel_launch(void* const* d_in, const int* in_sizes, int n_in,
                              void* d_out, int out_size, void* d_ws, size_t ws_size,
                              hipStream_t stream) {
    const float* x      = (const float*)d_in[0];
    const float* mem_in = (const float*)d_in[1];
    const float* ke_w   = (const float*)d_in[2];
    const float* ke_b   = (const float*)d_in[3];
    const float* km_w   = (const float*)d_in[4];
    const float* km_b   = (const float*)d_in[5];
    const float* kw2_w  = (const float*)d_in[6];
    const float* kw2_b  = (const float*)d_in[7];
    const float* sum_w  = (const float*)d_in[8];
    const float* sum_b  = (const float*)d_in[9];
    const float* out_w  = (const float*)d_in[10];
    const float* out_b  = (const float*)d_in[11];
    const float* ve_w   = (const float*)d_in[12];
    const float* ve_b   = (const float*)d_in[13];
    const float* er_w   = (const float*)d_in[14];
    const float* er_b   = (const float*)d_in[15];
    const float* ad_w   = (const float*)d_in[16];
    const float* ad_b   = (const float*)d_in[17];

    float* y_out   = (float*)d_out;
    float* mem_out = (float*)d_out + N_;

    // ---- workspace (float units, 16B-aligned offsets) ----
    float* ws = (float*)d_ws;
    size_t o = 0;
    float*  parts  = ws + o;            o += (size_t)NZ * N_ * 512;      // 4,194,304
    ushort* vw     = (ushort*)(ws + o); o += (size_t)N_ * KBIG / 2;      // 2,228,224
    ushort* Wcat   = (ushort*)(ws + o); o += (size_t)512 * KBIG / 2;     //   557,056
    ushort* kbuf   = (ushort*)(ws + o); o += (size_t)N_ * H_ / 2;        //   262,144
    ushort* x_bf   = (ushort*)(ws + o); o += (size_t)N_ * KX / 2;        //   425,984
    ushort* q_bf   = (ushort*)(ws + o); o += (size_t)N_ * KQ / 2;        //   229,376
    ushort* wbf    = (ushort*)(ws + o); o += (size_t)WC_KM / 2;          //   163,840 (ke|ve|sum|km)
    float*  v      = ws + o;            o += (size_t)N_ * H_;            //   524,288

    ushort* ke_bf  = wbf;
    ushort* ve_bf  = wbf + WC_KE;
    ushort* sum_bf = wbf + WC_VE;
    ushort* km_bf  = wbf + WC_SW;

    // 1. all prep/conversion/repack
    prep_all_kernel<<<P3 / 256, 256, 0, stream>>>(
        x, ke_w, ve_w, sum_w, km_w, er_w, er_b, ad_w, ad_b, x_bf, q_bf, wbf, Wcat);
    // 2. k = q @ ke_w.T + ke_b -> kbuf bf16
    gemm_mfma<1><<<dim3(H_ / 64, N_ / 128, 1), 256, 0, stream>>>(
        q_bf, KQ, ke_bf, KQ, ke_b, kbuf, H_, 0, KQ);
    // 3. v = x @ ve_w.T + ve_b -> f32
    gemm_mfma<0><<<dim3(H_ / 64, N_ / 128, 1), 256, 0, stream>>>(
        x_bf, KX, ve_bf, KX, ve_b, v, H_, 0, KX);
    // 4. w2 + vw fill
    vw_kernel<<<N_, 256, 0, stream>>>(kbuf, v, kw2_w, kw2_b, vw);
    // 5. big fused expert GEMM: parts[z] = vw @ Wcat.T, K split x4
    gemm_mfma<0><<<dim3(512 / 64, N_ / 128, NZ), 256, 0, stream>>>(
        vw, KBIG, Wcat, KBIG, nullptr, parts, 512, (size_t)N_ * 512, KSPL);
    // 6. mega-fused memory pass (+w softmax, e/a, r, f, y)
    mem_fused_kernel<<<N_, 256, 0, stream>>>(
        mem_in, parts, kbuf, km_bf, km_b, sum_bf, sum_b, out_w, out_b, mem_out, y_out);
}

// Round 5
// 203.557 us; speedup vs baseline: 1.1894x; 1.1894x over previous
//
#include <hip/hip_runtime.h>
#include <math.h>

#define N_  2048
#define IN_ 400
#define C_  200
#define H_  256
#define M_  128
#define D_  8

#define KQ   224   // C_=200 padded to x32
#define KX   416   // IN_=400 padded to x32
#define KBIG 2176  // 2048 data + 8 bias + 120 pad (68*32, /4 K-splittable)
#define NZ   4     // K-split of big GEMM
#define KSPL (KBIG / NZ)   // 544 = 17*32
#define KS   512   // [k | r] row stride

typedef __bf16 bf16x8 __attribute__((ext_vector_type(8)));
typedef float  f32x4  __attribute__((ext_vector_type(4)));

__device__ __forceinline__ ushort f2bf(float x) { __bf16 b = (__bf16)x; return __builtin_bit_cast(ushort, b); }
__device__ __forceinline__ float  bf2f(ushort u) { unsigned v = ((unsigned)u) << 16; return __builtin_bit_cast(float, v); }

// ---------------- prep_all: x_bf, q_bf, weight conversions, Wcat repack ----------------
#define P0 212992                  // x_bf: N * (KX/4)
#define P1 (P0 + 114688)           // q_bf: N * (KQ/4)
#define P2 (P1 + 81920)            // wconv: 327680/4 quads
#define P3 (P2 + 278528)           // Wcat: 512 * (KBIG/4)
#define WC_KE (256 * KQ)                 // 57344
#define WC_VE (WC_KE + 256 * KX)         // 163840
#define WC_SW (WC_VE + 256 * 512)        // 294912
#define WC_KM (WC_SW + 128 * 256)        // 327680
__global__ __launch_bounds__(256) void prep_all_kernel(
    const float* __restrict__ x,
    const float* __restrict__ ke, const float* __restrict__ ve,
    const float* __restrict__ sw, const float* __restrict__ km,
    const float* __restrict__ er_w, const float* __restrict__ er_b,
    const float* __restrict__ ad_w, const float* __restrict__ ad_b,
    ushort* __restrict__ x_bf, ushort* __restrict__ q_bf,
    ushort* __restrict__ wout, ushort* __restrict__ wcat)
{
    int idx = blockIdx.x * 256 + threadIdx.x;
    ushort pk[4];
    if (idx < P0) {
        int n = idx / (KX / 4), g = idx % (KX / 4), c0 = g * 4;
#pragma unroll
        for (int j = 0; j < 4; j++) {
            int c = c0 + j;
            pk[j] = f2bf((c < IN_) ? x[(size_t)n * IN_ + c] : 0.f);
        }
        *(ushort4*)&x_bf[(size_t)n * KX + c0] = *(ushort4*)pk;
    } else if (idx < P1) {
        int i = idx - P0;
        int n = i / (KQ / 4), g = i % (KQ / 4), c0 = g * 4;
#pragma unroll
        for (int j = 0; j < 4; j++) {
            int c = c0 + j;
            pk[j] = f2bf((c < C_) ? x[(size_t)n * IN_ + c] + x[(size_t)n * IN_ + C_ + c] : 0.f);
        }
        *(ushort4*)&q_bf[(size_t)n * KQ + c0] = *(ushort4*)pk;
    } else if (idx < P2) {
        int s0 = (idx - P1) * 4;
#pragma unroll
        for (int j = 0; j < 4; j++) {
            int s = s0 + j;
            float val;
            if (s < WC_KE)      { int r = s / KQ, c = s % KQ; val = (c < C_) ? ke[r * C_ + c] : 0.f; }
            else if (s < WC_VE) { int i = s - WC_KE; int r = i / KX, c = i % KX; val = (c < IN_) ? ve[r * IN_ + c] : 0.f; }
            else if (s < WC_SW) { val = sw[s - WC_VE]; }
            else                { val = km[s - WC_SW]; }
            pk[j] = f2bf(val);
        }
        *(ushort4*)&wout[s0] = *(ushort4*)pk;
    } else {
        int i = idx - P2;
        int o = i / (KBIG / 4), g = i % (KBIG / 4), c0 = g * 4;
        const float* Wsrc = (o < 256) ? er_w : ad_w;
        const float* bsrc = (o < 256) ? er_b : ad_b;
        int oo = o & 255;
#pragma unroll
        for (int j = 0; j < 4; j++) {
            int c = c0 + j;
            float val = 0.f;
            if (c < 2048)      { int d = c >> 8, ii = c & 255; val = Wsrc[(size_t)(d * 256 + oo) * 256 + ii]; }
            else if (c < 2056) { val = bsrc[(c - 2048) * 256 + oo]; }
            pk[j] = f2bf(val);
        }
        *(ushort4*)&wcat[(size_t)o * KBIG + c0] = *(ushort4*)pk;
    }
}

// ---------------- unified bf16 MFMA NT GEMM ----------------
// C[m,n] = act(sum_k A[m,k]*B[n,k] + bias[n]); tile 128x64, 4 waves (2x2),
// wave tile 64x32 -> 4x2 fragments 16x16, BK=32. z splits K (f32 out only).
template<int ACT, int OUTBF>
__global__ __launch_bounds__(256) void gemm_mfma(
    const ushort* __restrict__ A, int lda,
    const ushort* __restrict__ B, int ldb,
    const float* __restrict__ bias,
    void* __restrict__ Cv, int ldc, size_t csplit, int ksplit)
{
    constexpr int BM = 128, BN = 64;
    __shared__ ushort As[BM][40];
    __shared__ ushort Bs[BN][40];
    const int tid = threadIdx.x, lane = tid & 63, wave = tid >> 6;
    const int wm = (wave >> 1) * 64, wn = (wave & 1) * 32;
    const int m0 = blockIdx.y * BM, n0 = blockIdx.x * BN;
    const int kFrom = blockIdx.z * ksplit, kTo = kFrom + ksplit;

    f32x4 acc[4][2] = {};
    const int sr = tid >> 2;
    const int sc = (tid & 3) * 8;

    for (int k0 = kFrom; k0 < kTo; k0 += 32) {
        uint4 a0 = *(const uint4*)&A[(size_t)(m0 + sr) * lda + k0 + sc];
        uint4 a1 = *(const uint4*)&A[(size_t)(m0 + sr + 64) * lda + k0 + sc];
        uint4 b0 = *(const uint4*)&B[(size_t)(n0 + sr) * ldb + k0 + sc];
        *(uint4*)&As[sr][sc] = a0;
        *(uint4*)&As[sr + 64][sc] = a1;
        *(uint4*)&Bs[sr][sc] = b0;
        __syncthreads();

        const int ko = (lane >> 4) * 8;
        bf16x8 af[4], bfr[2];
#pragma unroll
        for (int i = 0; i < 4; i++)
            af[i] = __builtin_bit_cast(bf16x8, *(const uint4*)&As[wm + i * 16 + (lane & 15)][ko]);
#pragma unroll
        for (int j = 0; j < 2; j++)
            bfr[j] = __builtin_bit_cast(bf16x8, *(const uint4*)&Bs[wn + j * 16 + (lane & 15)][ko]);
#pragma unroll
        for (int i = 0; i < 4; i++)
#pragma unroll
            for (int j = 0; j < 2; j++)
                acc[i][j] = __builtin_amdgcn_mfma_f32_16x16x32_bf16(af[i], bfr[j], acc[i][j], 0, 0, 0);
        __syncthreads();
    }

    float* Cf = (float*)Cv + blockIdx.z * csplit;
    ushort* Cb = (ushort*)Cv;
#pragma unroll
    for (int i = 0; i < 4; i++) {
#pragma unroll
        for (int j = 0; j < 2; j++) {
            int row = m0 + wm + i * 16 + (lane >> 4) * 4;
            int col = n0 + wn + j * 16 + (lane & 15);
#pragma unroll
            for (int r = 0; r < 4; r++) {
                float val = acc[i][j][r];
                if (bias) val += bias[col];
                if (ACT == 1) val = tanhf(val);
                if (OUTBF) Cb[(size_t)(row + r) * ldc + col] = f2bf(val);
                else       Cf[(size_t)(row + r) * ldc + col] = val;
            }
        }
    }
}

// ---------------- vw: per-n w2 (dots + softmax D=8) then vw row fill ----------------
__global__ __launch_bounds__(256) void vw_kernel(
    const ushort* __restrict__ kr, const float* __restrict__ v,
    const float* __restrict__ kw2_w, const float* __restrict__ kw2_b,
    ushort* __restrict__ vw)
{
    __shared__ float kf[H_], vl[H_], lg[8], w2l[8];
    const int n = blockIdx.x, t = threadIdx.x;
    if (t < 64) {
        ushort4 u = ((const ushort4*)(kr + (size_t)n * KS))[t];
        kf[t * 4 + 0] = bf2f(u.x); kf[t * 4 + 1] = bf2f(u.y);
        kf[t * 4 + 2] = bf2f(u.z); kf[t * 4 + 3] = bf2f(u.w);
        float4 vv = ((const float4*)(v + (size_t)n * H_))[t];
        vl[t * 4 + 0] = vv.x; vl[t * 4 + 1] = vv.y;
        vl[t * 4 + 2] = vv.z; vl[t * 4 + 3] = vv.w;
    }
    __syncthreads();
    {
        int d = t >> 5, l = t & 31;
        float acc = 0.f;
        const float* wr = kw2_w + d * H_;
#pragma unroll
        for (int s = 0; s < 8; s++) acc += kf[l + 32 * s] * wr[l + 32 * s];
#pragma unroll
        for (int off = 16; off; off >>= 1) acc += __shfl_xor(acc, off);
        if (l == 0) lg[d] = acc + kw2_b[d];
    }
    __syncthreads();
    if (t < 8) {
        float val = lg[t];
        float mx = val;
#pragma unroll
        for (int off = 1; off < 8; off <<= 1) mx = fmaxf(mx, __shfl_xor(mx, off));
        float e = expf(val - mx), s = e;
#pragma unroll
        for (int off = 1; off < 8; off <<= 1) s += __shfl_xor(s, off);
        w2l[t] = e / s;
    }
    __syncthreads();
    ushort* row = vw + (size_t)n * KBIG;
    for (int g = t; g < KBIG / 4; g += 256) {
        int c0 = g * 4;
        ushort pk[4];
#pragma unroll
        for (int j = 0; j < 4; j++) {
            int c = c0 + j;
            float val = 0.f;
            if (c < 2048)      val = w2l[c >> 8] * vl[c & 255];
            else if (c < 2056) val = w2l[c - 2048];
            pk[j] = f2bf(val);
        }
        *(ushort4*)&row[c0] = *(ushort4*)pk;
    }
}

// ---------------- pure streaming memory pass ----------------
// block = (n, half): softmax(wlog[n]) -> wl; e/a from parts (own 128 h's);
// stream 128 rows: r-reduce -> kr[:,256+h] bf16 ; erase/add -> mem_out
__global__ __launch_bounds__(256) void mem_stream_kernel(
    const float* __restrict__ mem_in,
    const float* __restrict__ wlog,        // N x 128 logits
    const float* __restrict__ parts,       // NZ x N x 512
    float* __restrict__ mem_out,
    ushort* __restrict__ kr)
{
    __shared__ float wl[M_];
    __shared__ float el[128], al[128];
    __shared__ float red[4];
    const int n = blockIdx.x >> 1, half = blockIdx.x & 1, hbase = half * 128;
    const int t = threadIdx.x;

    // parts sum for this block's 128 h's: t<128 -> e-col, t>=128 -> a-col
    const int col = (t < 128) ? (hbase + t) : (256 + hbase + (t - 128));
    float pacc = 0.f;
#pragma unroll
    for (int z = 0; z < NZ; z++)
        pacc += parts[(size_t)z * N_ * 512 + (size_t)n * 512 + col];

    float lv = 0.f;
    if (t < 128) {
        lv = wlog[(size_t)n * M_ + t];
        float mx = lv;
#pragma unroll
        for (int off = 32; off; off >>= 1) mx = fmaxf(mx, __shfl_xor(mx, off));
        if ((t & 63) == 0) red[t >> 6] = mx;
        el[t] = 1.f / (1.f + expf(-pacc));
    } else {
        al[t - 128] = tanhf(pacc);
    }
    __syncthreads();
    if (t < 128) {
        float gmax = fmaxf(red[0], red[1]);
        float ev = expf(lv - gmax);
        float s = ev;
#pragma unroll
        for (int off = 32; off; off >>= 1) s += __shfl_xor(s, off);
        if ((t & 63) == 0) red[2 + (t >> 6)] = s;
        wl[t] = ev;
    }
    __syncthreads();
    if (t < 128) wl[t] *= 1.f / (red[2] + red[3]);
    __syncthreads();

    // stream 128 rows (h in [hbase, hbase+128))
    const int wave = t >> 6, lane = t & 63, half2 = lane >> 5, l32 = lane & 31;
    const float4* min4 = (const float4*)(mem_in + ((size_t)n * H_ + hbase) * M_);
    float4* mout4 = (float4*)(mem_out + ((size_t)n * H_ + hbase) * M_);
    float4 wv = ((const float4*)wl)[l32];
#pragma unroll 4
    for (int i = 0; i < 16; i++) {
        int hl = i * 8 + wave * 2 + half2;   // 0..127
        float4 mv = min4[hl * 32 + l32];
        float eh = el[hl], ah = al[hl];
        float4 nv;
        nv.x = mv.x * (1.f - wv.x * eh) + wv.x * ah;
        nv.y = mv.y * (1.f - wv.y * eh) + wv.y * ah;
        nv.z = mv.z * (1.f - wv.z * eh) + wv.z * ah;
        nv.w = mv.w * (1.f - wv.w * eh) + wv.w * ah;
        mout4[hl * 32 + l32] = nv;
        float racc = mv.x * wv.x + mv.y * wv.y + mv.z * wv.z + mv.w * wv.w;
#pragma unroll
        for (int off = 1; off < 32; off <<= 1) racc += __shfl_xor(racc, off);
        if (l32 == 0) kr[(size_t)n * KS + H_ + hbase + hl] = f2bf(racc);
    }
}

// ---------------- y[n] = f[n,:] . out_w + out_b ----------------
__global__ void y_kernel(const float* __restrict__ f, const float* __restrict__ out_w,
                         const float* __restrict__ out_b, float* __restrict__ y) {
    int n = blockIdx.x, t = threadIdx.x;  // 64
    float acc = 0.f;
#pragma unroll
    for (int j = 0; j < 4; j++) acc += f[(size_t)n * H_ + t + j * 64] * out_w[t + j * 64];
#pragma unroll
    for (int off = 32; off; off >>= 1) acc += __shfl_xor(acc, off);
    if (t == 0) y[n] = acc + out_b[0];
}

extern "C" void kernel_launch(void* const* d_in, const int* in_sizes, int n_in,
                              void* d_out, int out_size, void* d_ws, size_t ws_size,
                              hipStream_t stream) {
    const float* x      = (const float*)d_in[0];
    const float* mem_in = (const float*)d_in[1];
    const float* ke_w   = (const float*)d_in[2];
    const float* ke_b   = (const float*)d_in[3];
    const float* km_w   = (const float*)d_in[4];
    const float* km_b   = (const float*)d_in[5];
    const float* kw2_w  = (const float*)d_in[6];
    const float* kw2_b  = (const float*)d_in[7];
    const float* sum_w  = (const float*)d_in[8];
    const float* sum_b  = (const float*)d_in[9];
    const float* out_w  = (const float*)d_in[10];
    const float* out_b  = (const float*)d_in[11];
    const float* ve_w   = (const float*)d_in[12];
    const float* ve_b   = (const float*)d_in[13];
    const float* er_w   = (const float*)d_in[14];
    const float* er_b   = (const float*)d_in[15];
    const float* ad_w   = (const float*)d_in[16];
    const float* ad_b   = (const float*)d_in[17];

    float* y_out   = (float*)d_out;
    float* mem_out = (float*)d_out + N_;

    // ---- workspace (float units, 16B-aligned offsets) ----
    float* ws = (float*)d_ws;
    size_t o = 0;
    float*  parts  = ws + o;            o += (size_t)NZ * N_ * 512;      // 4,194,304
    ushort* vw     = (ushort*)(ws + o); o += (size_t)N_ * KBIG / 2;      // 2,228,224
    ushort* Wcat   = (ushort*)(ws + o); o += (size_t)512 * KBIG / 2;     //   557,056
    ushort* kr     = (ushort*)(ws + o); o += (size_t)N_ * KS / 2;        //   524,288
    ushort* x_bf   = (ushort*)(ws + o); o += (size_t)N_ * KX / 2;        //   425,984
    ushort* q_bf   = (ushort*)(ws + o); o += (size_t)N_ * KQ / 2;        //   229,376
    ushort* wbf    = (ushort*)(ws + o); o += (size_t)WC_KM / 2;          //   163,840
    float*  v      = ws + o;            o += (size_t)N_ * H_;            //   524,288
    float*  wlog   = ws + o;            o += (size_t)N_ * M_;            //   262,144
    // fbuf aliases x_bf/q_bf (both dead after the v/k GEMMs, before f-GEMM)
    float*  fbuf   = (float*)x_bf;                                        //   524,288 fits 655,360

    ushort* ke_bf  = wbf;
    ushort* ve_bf  = wbf + WC_KE;
    ushort* sum_bf = wbf + WC_VE;
    ushort* km_bf  = wbf + WC_SW;

    // 1. all prep/conversion/repack
    prep_all_kernel<<<P3 / 256, 256, 0, stream>>>(
        x, ke_w, ve_w, sum_w, km_w, er_w, er_b, ad_w, ad_b, x_bf, q_bf, wbf, Wcat);
    // 2. k = q @ ke_w.T + ke_b -> kr[:, 0:256] bf16
    gemm_mfma<0, 1><<<dim3(H_ / 64, N_ / 128, 1), 256, 0, stream>>>(
        q_bf, KQ, ke_bf, KQ, ke_b, kr, KS, 0, KQ);
    // 3. v = x @ ve_w.T + ve_b -> f32
    gemm_mfma<0, 0><<<dim3(H_ / 64, N_ / 128, 1), 256, 0, stream>>>(
        x_bf, KX, ve_bf, KX, ve_b, v, H_, 0, KX);
    // 4. w2 + vw fill
    vw_kernel<<<N_, 256, 0, stream>>>(kr, v, kw2_w, kw2_b, vw);
    // 5. big fused expert GEMM: parts[z] = vw @ Wcat.T, K split x4
    gemm_mfma<0, 0><<<dim3(512 / 64, N_ / 128, NZ), 256, 0, stream>>>(
        vw, KBIG, Wcat, KBIG, nullptr, parts, 512, (size_t)N_ * 512, KSPL);
    // 6. w logits = k @ km_w.T + km_b
    gemm_mfma<0, 0><<<dim3(M_ / 64, N_ / 128, 1), 256, 0, stream>>>(
        kr, KS, km_bf, H_, km_b, wlog, M_, 0, H_);
    // 7. pure streaming memory pass (softmax + e/a prologue)
    mem_stream_kernel<<<2 * N_, 256, 0, stream>>>(mem_in, wlog, parts, mem_out, kr);
    // 8. f = tanh(kr @ sum_w.T + sum_b)
    gemm_mfma<1, 0><<<dim3(H_ / 64, N_ / 128, 1), 256, 0, stream>>>(
        kr, KS, sum_bf, KS, sum_b, fbuf, H_, 0, KS);
    // 9. y
    y_kernel<<<N_, 64, 0, stream>>>(fbuf, out_w, out_b, y_out);
}

// Round 6
// 170.395 us; speedup vs baseline: 1.4209x; 1.1946x over previous
//
#include <hip/hip_runtime.h>
#include <math.h>

#define N_  2048
#define IN_ 400
#define C_  200
#define H_  256
#define M_  128
#define D_  8

#define KQ   224   // C_=200 padded to x32
#define KX   416   // IN_=400 padded to x32
#define KBIG 2176  // 2048 data + 8 bias + 120 pad (68*32, /4 K-splittable)
#define NZ   4     // K-split of big GEMM
#define KSPL (KBIG / NZ)   // 544 = 17*32
#define KS   512   // [k | r] row stride

typedef __bf16 bf16x8 __attribute__((ext_vector_type(8)));
typedef float  f32x4  __attribute__((ext_vector_type(4)));

__device__ __forceinline__ ushort f2bf(float x) { __bf16 b = (__bf16)x; return __builtin_bit_cast(ushort, b); }
__device__ __forceinline__ float  bf2f(ushort u) { unsigned v = ((unsigned)u) << 16; return __builtin_bit_cast(float, v); }

// ---------------- prep_all: x_bf, q_bf, weight conversions, Wcat repack ----------------
#define P0 212992                  // x_bf: N * (KX/4)
#define P1 (P0 + 114688)           // q_bf: N * (KQ/4)
#define P2 (P1 + 81920)            // wconv: 327680/4 quads
#define P3 (P2 + 278528)           // Wcat: 512 * (KBIG/4)
#define WC_KE (256 * KQ)                 // 57344
#define WC_VE (WC_KE + 256 * KX)         // 163840
#define WC_SW (WC_VE + 256 * 512)        // 294912
#define WC_KM (WC_SW + 128 * 256)        // 327680
__global__ __launch_bounds__(256) void prep_all_kernel(
    const float* __restrict__ x,
    const float* __restrict__ ke, const float* __restrict__ ve,
    const float* __restrict__ sw, const float* __restrict__ km,
    const float* __restrict__ er_w, const float* __restrict__ er_b,
    const float* __restrict__ ad_w, const float* __restrict__ ad_b,
    ushort* __restrict__ x_bf, ushort* __restrict__ q_bf,
    ushort* __restrict__ wout, ushort* __restrict__ wcat)
{
    int idx = blockIdx.x * 256 + threadIdx.x;
    ushort pk[4];
    if (idx < P0) {
        int n = idx / (KX / 4), g = idx % (KX / 4), c0 = g * 4;
#pragma unroll
        for (int j = 0; j < 4; j++) {
            int c = c0 + j;
            pk[j] = f2bf((c < IN_) ? x[(size_t)n * IN_ + c] : 0.f);
        }
        *(ushort4*)&x_bf[(size_t)n * KX + c0] = *(ushort4*)pk;
    } else if (idx < P1) {
        int i = idx - P0;
        int n = i / (KQ / 4), g = i % (KQ / 4), c0 = g * 4;
#pragma unroll
        for (int j = 0; j < 4; j++) {
            int c = c0 + j;
            pk[j] = f2bf((c < C_) ? x[(size_t)n * IN_ + c] + x[(size_t)n * IN_ + C_ + c] : 0.f);
        }
        *(ushort4*)&q_bf[(size_t)n * KQ + c0] = *(ushort4*)pk;
    } else if (idx < P2) {
        int s0 = (idx - P1) * 4;
#pragma unroll
        for (int j = 0; j < 4; j++) {
            int s = s0 + j;
            float val;
            if (s < WC_KE)      { int r = s / KQ, c = s % KQ; val = (c < C_) ? ke[r * C_ + c] : 0.f; }
            else if (s < WC_VE) { int i = s - WC_KE; int r = i / KX, c = i % KX; val = (c < IN_) ? ve[r * IN_ + c] : 0.f; }
            else if (s < WC_SW) { val = sw[s - WC_VE]; }
            else                { val = km[s - WC_SW]; }
            pk[j] = f2bf(val);
        }
        *(ushort4*)&wout[s0] = *(ushort4*)pk;
    } else {
        int i = idx - P2;
        int o = i / (KBIG / 4), g = i % (KBIG / 4), c0 = g * 4;
        const float* Wsrc = (o < 256) ? er_w : ad_w;
        const float* bsrc = (o < 256) ? er_b : ad_b;
        int oo = o & 255;
#pragma unroll
        for (int j = 0; j < 4; j++) {
            int c = c0 + j;
            float val = 0.f;
            if (c < 2048)      { int d = c >> 8, ii = c & 255; val = Wsrc[(size_t)(d * 256 + oo) * 256 + ii]; }
            else if (c < 2056) { val = bsrc[(c - 2048) * 256 + oo]; }
            pk[j] = f2bf(val);
        }
        *(ushort4*)&wcat[(size_t)o * KBIG + c0] = *(ushort4*)pk;
    }
}

// ---------------- double-buffered 128x64 MFMA GEMM core ----------------
// C[m,n] = sum_k A[m,k]*B[n,k] (+bias[n]); 4 waves (2x2), wave tile 64x32,
// acc 4x2 fragments of 16x16, BK=32, reg-prefetch + LDS double buffer.
__device__ __forceinline__ void gemm_core_128x64(
    const ushort* __restrict__ A, int lda,
    const ushort* __restrict__ B, int ldb,
    const float* __restrict__ bias,
    void* __restrict__ Cv, int ldc, int outbf,
    int m0, int n0, int kFrom, int kTo,
    ushort (*As)[128][40], ushort (*Bs)[64][40])
{
    const int tid = threadIdx.x, lane = tid & 63, wave = tid >> 6;
    const int wm = (wave >> 1) * 64, wn = (wave & 1) * 32;
    const int sr = tid >> 2, sc = (tid & 3) * 8;

    f32x4 acc[4][2] = {};

    auto compute = [&](int b) {
        const int ko = (lane >> 4) * 8;
        bf16x8 af[4], bfr[2];
#pragma unroll
        for (int i = 0; i < 4; i++)
            af[i] = __builtin_bit_cast(bf16x8, *(const uint4*)&As[b][wm + i * 16 + (lane & 15)][ko]);
#pragma unroll
        for (int j = 0; j < 2; j++)
            bfr[j] = __builtin_bit_cast(bf16x8, *(const uint4*)&Bs[b][wn + j * 16 + (lane & 15)][ko]);
#pragma unroll
        for (int i = 0; i < 4; i++)
#pragma unroll
            for (int j = 0; j < 2; j++)
                acc[i][j] = __builtin_amdgcn_mfma_f32_16x16x32_bf16(af[i], bfr[j], acc[i][j], 0, 0, 0);
    };

    uint4 a0 = *(const uint4*)&A[(size_t)(m0 + sr) * lda + kFrom + sc];
    uint4 a1 = *(const uint4*)&A[(size_t)(m0 + sr + 64) * lda + kFrom + sc];
    uint4 b0 = *(const uint4*)&B[(size_t)(n0 + sr) * ldb + kFrom + sc];
    *(uint4*)&As[0][sr][sc] = a0;
    *(uint4*)&As[0][sr + 64][sc] = a1;
    *(uint4*)&Bs[0][sr][sc] = b0;
    __syncthreads();

    int cur = 0;
    for (int k0 = kFrom + 32; k0 < kTo; k0 += 32) {
        a0 = *(const uint4*)&A[(size_t)(m0 + sr) * lda + k0 + sc];
        a1 = *(const uint4*)&A[(size_t)(m0 + sr + 64) * lda + k0 + sc];
        b0 = *(const uint4*)&B[(size_t)(n0 + sr) * ldb + k0 + sc];
        compute(cur);
        *(uint4*)&As[cur ^ 1][sr][sc] = a0;
        *(uint4*)&As[cur ^ 1][sr + 64][sc] = a1;
        *(uint4*)&Bs[cur ^ 1][sr][sc] = b0;
        __syncthreads();
        cur ^= 1;
    }
    compute(cur);

    float* Cf = (float*)Cv;
    ushort* Cb = (ushort*)Cv;
#pragma unroll
    for (int i = 0; i < 4; i++) {
#pragma unroll
        for (int j = 0; j < 2; j++) {
            int row = m0 + wm + i * 16 + (lane >> 4) * 4;
            int col = n0 + wn + j * 16 + (lane & 15);
#pragma unroll
            for (int r = 0; r < 4; r++) {
                float val = acc[i][j][r];
                if (bias) val += bias[col];
                if (outbf) Cb[(size_t)(row + r) * ldc + col] = f2bf(val);
                else       Cf[(size_t)(row + r) * ldc + col] = val;
            }
        }
    }
}

// ---------------- kv: z=0 -> k GEMM (bf16 out into kr), z=1 -> v GEMM (f32) ----
__global__ __launch_bounds__(256) void kv_kernel(
    const ushort* __restrict__ q_bf, const ushort* __restrict__ ke_bf,
    const float* __restrict__ ke_b, ushort* __restrict__ kr,
    const ushort* __restrict__ x_bf, const ushort* __restrict__ ve_bf,
    const float* __restrict__ ve_b, float* __restrict__ v)
{
    __shared__ ushort As[2][128][40];
    __shared__ ushort Bs[2][64][40];
    if (blockIdx.z == 0)
        gemm_core_128x64(q_bf, KQ, ke_bf, KQ, ke_b, kr, KS, 1,
                         blockIdx.y * 128, blockIdx.x * 64, 0, KQ, As, Bs);
    else
        gemm_core_128x64(x_bf, KX, ve_bf, KX, ve_b, v, H_, 0,
                         blockIdx.y * 128, blockIdx.x * 64, 0, KX, As, Bs);
}

// ---------------- bigw: z<NZ -> big expert GEMM K-slice; z==NZ -> wlog GEMM ----
__global__ __launch_bounds__(256) void bigw_kernel(
    const ushort* __restrict__ vw, const ushort* __restrict__ Wcat,
    float* __restrict__ parts,
    const ushort* __restrict__ kr, const ushort* __restrict__ km_bf,
    const float* __restrict__ km_b, float* __restrict__ wlog)
{
    __shared__ ushort As[2][128][40];
    __shared__ ushort Bs[2][64][40];
    const int z = blockIdx.z;
    if (z < NZ) {
        gemm_core_128x64(vw, KBIG, Wcat, KBIG, nullptr,
                         parts + (size_t)z * N_ * 512, 512, 0,
                         blockIdx.y * 128, blockIdx.x * 64, z * KSPL, (z + 1) * KSPL, As, Bs);
    } else {
        if (blockIdx.x >= 2) return;
        gemm_core_128x64(kr, KS, km_bf, H_, km_b, wlog, M_, 0,
                         blockIdx.y * 128, blockIdx.x * 64, 0, H_, As, Bs);
    }
}

// ---------------- vw: per-n w2 (dots + softmax D=8) then vw row fill ----------------
__global__ __launch_bounds__(256) void vw_kernel(
    const ushort* __restrict__ kr, const float* __restrict__ v,
    const float* __restrict__ kw2_w, const float* __restrict__ kw2_b,
    ushort* __restrict__ vw)
{
    __shared__ float kf[H_], vl[H_], lg[8], w2l[8];
    const int n = blockIdx.x, t = threadIdx.x;
    if (t < 64) {
        ushort4 u = ((const ushort4*)(kr + (size_t)n * KS))[t];
        kf[t * 4 + 0] = bf2f(u.x); kf[t * 4 + 1] = bf2f(u.y);
        kf[t * 4 + 2] = bf2f(u.z); kf[t * 4 + 3] = bf2f(u.w);
        float4 vv = ((const float4*)(v + (size_t)n * H_))[t];
        vl[t * 4 + 0] = vv.x; vl[t * 4 + 1] = vv.y;
        vl[t * 4 + 2] = vv.z; vl[t * 4 + 3] = vv.w;
    }
    __syncthreads();
    {
        int d = t >> 5, l = t & 31;
        float acc = 0.f;
        const float* wr = kw2_w + d * H_;
#pragma unroll
        for (int s = 0; s < 8; s++) acc += kf[l + 32 * s] * wr[l + 32 * s];
#pragma unroll
        for (int off = 16; off; off >>= 1) acc += __shfl_xor(acc, off);
        if (l == 0) lg[d] = acc + kw2_b[d];
    }
    __syncthreads();
    if (t < 8) {
        float val = lg[t];
        float mx = val;
#pragma unroll
        for (int off = 1; off < 8; off <<= 1) mx = fmaxf(mx, __shfl_xor(mx, off));
        float e = expf(val - mx), s = e;
#pragma unroll
        for (int off = 1; off < 8; off <<= 1) s += __shfl_xor(s, off);
        w2l[t] = e / s;
    }
    __syncthreads();
    ushort* row = vw + (size_t)n * KBIG;
    for (int g = t; g < KBIG / 4; g += 256) {
        int c0 = g * 4;
        ushort pk[4];
#pragma unroll
        for (int j = 0; j < 4; j++) {
            int c = c0 + j;
            float val = 0.f;
            if (c < 2048)      val = w2l[c >> 8] * vl[c & 255];
            else if (c < 2056) val = w2l[c - 2048];
            pk[j] = f2bf(val);
        }
        *(ushort4*)&row[c0] = *(ushort4*)pk;
    }
}

// ---------------- pure streaming memory pass (nontemporal) ----------------
__global__ __launch_bounds__(256) void mem_stream_kernel(
    const float* __restrict__ mem_in,
    const float* __restrict__ wlog,        // N x 128 logits
    const float* __restrict__ parts,       // NZ x N x 512
    float* __restrict__ mem_out,
    ushort* __restrict__ kr)
{
    __shared__ float wl[M_];
    __shared__ float el[128], al[128];
    __shared__ float red[4];
    const int n = blockIdx.x >> 1, half = blockIdx.x & 1, hbase = half * 128;
    const int t = threadIdx.x;

    const int col = (t < 128) ? (hbase + t) : (256 + hbase + (t - 128));
    float pacc = 0.f;
#pragma unroll
    for (int z = 0; z < NZ; z++)
        pacc += parts[(size_t)z * N_ * 512 + (size_t)n * 512 + col];

    float lv = 0.f;
    if (t < 128) {
        lv = wlog[(size_t)n * M_ + t];
        float mx = lv;
#pragma unroll
        for (int off = 32; off; off >>= 1) mx = fmaxf(mx, __shfl_xor(mx, off));
        if ((t & 63) == 0) red[t >> 6] = mx;
        el[t] = 1.f / (1.f + expf(-pacc));
    } else {
        al[t - 128] = tanhf(pacc);
    }
    __syncthreads();
    if (t < 128) {
        float gmax = fmaxf(red[0], red[1]);
        float ev = expf(lv - gmax);
        float s = ev;
#pragma unroll
        for (int off = 32; off; off >>= 1) s += __shfl_xor(s, off);
        if ((t & 63) == 0) red[2 + (t >> 6)] = s;
        wl[t] = ev;
    }
    __syncthreads();
    if (t < 128) wl[t] *= 1.f / (red[2] + red[3]);
    __syncthreads();

    const int wave = t >> 6, lane = t & 63, half2 = lane >> 5, l32 = lane & 31;
    const f32x4* min4 = (const f32x4*)(mem_in + ((size_t)n * H_ + hbase) * M_);
    f32x4* mout4 = (f32x4*)(mem_out + ((size_t)n * H_ + hbase) * M_);
    f32x4 wv = ((const f32x4*)wl)[l32];
#pragma unroll 4
    for (int i = 0; i < 16; i++) {
        int hl = i * 8 + wave * 2 + half2;   // 0..127
        f32x4 mv = __builtin_nontemporal_load(&min4[hl * 32 + l32]);
        float eh = el[hl], ah = al[hl];
        f32x4 nv = mv * (1.f - wv * eh) + wv * ah;
        __builtin_nontemporal_store(nv, &mout4[hl * 32 + l32]);
        float racc = mv[0] * wv[0] + mv[1] * wv[1] + mv[2] * wv[2] + mv[3] * wv[3];
#pragma unroll
        for (int off = 1; off < 32; off <<= 1) racc += __shfl_xor(racc, off);
        if (l32 == 0) kr[(size_t)n * KS + H_ + hbase + hl] = f2bf(racc);
    }
}

// ---------------- fy: f = tanh(kr @ sum_w.T + sum_b) fused into y = f.out_w + out_b ----
// BM=64 rows x BN=256 cols (full), K=512; 4 waves 1x4; f never leaves the block.
__global__ __launch_bounds__(256) void fy_kernel(
    const ushort* __restrict__ kr, const ushort* __restrict__ sum_bf,
    const float* __restrict__ sum_b, const float* __restrict__ out_w,
    const float* __restrict__ out_b, float* __restrict__ y)
{
    __shared__ ushort As[2][64][40];
    __shared__ ushort Bs[2][256][40];
    __shared__ float yl[64][4];
    const int tid = threadIdx.x, lane = tid & 63, wave = tid >> 6;
    const int wn = wave * 64;
    const int m0 = blockIdx.x * 64;
    const int sr = tid >> 2, sc = (tid & 3) * 8;

    f32x4 acc[4][4] = {};

    auto compute = [&](int b) {
        const int ko = (lane >> 4) * 8;
        bf16x8 af[4], bfr[4];
#pragma unroll
        for (int i = 0; i < 4; i++)
            af[i] = __builtin_bit_cast(bf16x8, *(const uint4*)&As[b][i * 16 + (lane & 15)][ko]);
#pragma unroll
        for (int j = 0; j < 4; j++)
            bfr[j] = __builtin_bit_cast(bf16x8, *(const uint4*)&Bs[b][wn + j * 16 + (lane & 15)][ko]);
#pragma unroll
        for (int i = 0; i < 4; i++)
#pragma unroll
            for (int j = 0; j < 4; j++)
                acc[i][j] = __builtin_amdgcn_mfma_f32_16x16x32_bf16(af[i], bfr[j], acc[i][j], 0, 0, 0);
    };

    uint4 a0 = *(const uint4*)&kr[(size_t)(m0 + sr) * KS + 0 + sc];
    uint4 b0 = *(const uint4*)&sum_bf[(size_t)(sr)       * KS + 0 + sc];
    uint4 b1 = *(const uint4*)&sum_bf[(size_t)(sr + 64)  * KS + 0 + sc];
    uint4 b2 = *(const uint4*)&sum_bf[(size_t)(sr + 128) * KS + 0 + sc];
    uint4 b3 = *(const uint4*)&sum_bf[(size_t)(sr + 192) * KS + 0 + sc];
    *(uint4*)&As[0][sr][sc] = a0;
    *(uint4*)&Bs[0][sr][sc] = b0;
    *(uint4*)&Bs[0][sr + 64][sc] = b1;
    *(uint4*)&Bs[0][sr + 128][sc] = b2;
    *(uint4*)&Bs[0][sr + 192][sc] = b3;
    __syncthreads();

    int cur = 0;
    for (int k0 = 32; k0 < KS; k0 += 32) {
        a0 = *(const uint4*)&kr[(size_t)(m0 + sr) * KS + k0 + sc];
        b0 = *(const uint4*)&sum_bf[(size_t)(sr)       * KS + k0 + sc];
        b1 = *(const uint4*)&sum_bf[(size_t)(sr + 64)  * KS + k0 + sc];
        b2 = *(const uint4*)&sum_bf[(size_t)(sr + 128) * KS + k0 + sc];
        b3 = *(const uint4*)&sum_bf[(size_t)(sr + 192) * KS + k0 + sc];
        compute(cur);
        *(uint4*)&As[cur ^ 1][sr][sc] = a0;
        *(uint4*)&Bs[cur ^ 1][sr][sc] = b0;
        *(uint4*)&Bs[cur ^ 1][sr + 64][sc] = b1;
        *(uint4*)&Bs[cur ^ 1][sr + 128][sc] = b2;
        *(uint4*)&Bs[cur ^ 1][sr + 192][sc] = b3;
        __syncthreads();
        cur ^= 1;
    }
    compute(cur);

    // epilogue: f=tanh(acc+sum_b[col]); y-partial = sum_cols f*out_w[col]
    float ow[4], sb[4];
#pragma unroll
    for (int j = 0; j < 4; j++) {
        int col = wn + j * 16 + (lane & 15);
        ow[j] = out_w[col];
        sb[j] = sum_b[col];
    }
    float yp[4][4];
#pragma unroll
    for (int i = 0; i < 4; i++)
#pragma unroll
        for (int r = 0; r < 4; r++) {
            float s = 0.f;
#pragma unroll
            for (int j = 0; j < 4; j++)
                s += tanhf(acc[i][j][r] + sb[j]) * ow[j];
            yp[i][r] = s;
        }
#pragma unroll
    for (int off = 1; off < 16; off <<= 1)
#pragma unroll
        for (int i = 0; i < 4; i++)
#pragma unroll
            for (int r = 0; r < 4; r++)
                yp[i][r] += __shfl_xor(yp[i][r], off);
    if ((lane & 15) == 0) {
#pragma unroll
        for (int i = 0; i < 4; i++)
#pragma unroll
            for (int r = 0; r < 4; r++)
                yl[i * 16 + (lane >> 4) * 4 + r][wave] = yp[i][r];
    }
    __syncthreads();
    if (tid < 64)
        y[m0 + tid] = yl[tid][0] + yl[tid][1] + yl[tid][2] + yl[tid][3] + out_b[0];
}

extern "C" void kernel_launch(void* const* d_in, const int* in_sizes, int n_in,
                              void* d_out, int out_size, void* d_ws, size_t ws_size,
                              hipStream_t stream) {
    const float* x      = (const float*)d_in[0];
    const float* mem_in = (const float*)d_in[1];
    const float* ke_w   = (const float*)d_in[2];
    const float* ke_b   = (const float*)d_in[3];
    const float* km_w   = (const float*)d_in[4];
    const float* km_b   = (const float*)d_in[5];
    const float* kw2_w  = (const float*)d_in[6];
    const float* kw2_b  = (const float*)d_in[7];
    const float* sum_w  = (const float*)d_in[8];
    const float* sum_b  = (const float*)d_in[9];
    const float* out_w  = (const float*)d_in[10];
    const float* out_b  = (const float*)d_in[11];
    const float* ve_w   = (const float*)d_in[12];
    const float* ve_b   = (const float*)d_in[13];
    const float* er_w   = (const float*)d_in[14];
    const float* er_b   = (const float*)d_in[15];
    const float* ad_w   = (const float*)d_in[16];
    const float* ad_b   = (const float*)d_in[17];

    float* y_out   = (float*)d_out;
    float* mem_out = (float*)d_out + N_;

    // ---- workspace (float units, 16B-aligned offsets) ----
    float* ws = (float*)d_ws;
    size_t o = 0;
    float*  parts  = ws + o;            o += (size_t)NZ * N_ * 512;      // 4,194,304
    ushort* vw     = (ushort*)(ws + o); o += (size_t)N_ * KBIG / 2;      // 2,228,224
    ushort* Wcat   = (ushort*)(ws + o); o += (size_t)512 * KBIG / 2;     //   557,056
    ushort* kr     = (ushort*)(ws + o); o += (size_t)N_ * KS / 2;        //   524,288
    ushort* x_bf   = (ushort*)(ws + o); o += (size_t)N_ * KX / 2;        //   425,984
    ushort* q_bf   = (ushort*)(ws + o); o += (size_t)N_ * KQ / 2;        //   229,376
    ushort* wbf    = (ushort*)(ws + o); o += (size_t)WC_KM / 2;          //   163,840
    float*  v      = ws + o;            o += (size_t)N_ * H_;            //   524,288
    float*  wlog   = ws + o;            o += (size_t)N_ * M_;            //   262,144

    ushort* ke_bf  = wbf;
    ushort* ve_bf  = wbf + WC_KE;
    ushort* sum_bf = wbf + WC_VE;
    ushort* km_bf  = wbf + WC_SW;

    // 1. all prep/conversion/repack
    prep_all_kernel<<<P3 / 256, 256, 0, stream>>>(
        x, ke_w, ve_w, sum_w, km_w, er_w, er_b, ad_w, ad_b, x_bf, q_bf, wbf, Wcat);
    // 2. k -> kr[:,0:256] (z=0) and v (z=1), one launch
    kv_kernel<<<dim3(4, 16, 2), 256, 0, stream>>>(
        q_bf, ke_bf, ke_b, kr, x_bf, ve_bf, ve_b, v);
    // 3. w2 + vw fill
    vw_kernel<<<N_, 256, 0, stream>>>(kr, v, kw2_w, kw2_b, vw);
    // 4. big expert GEMM (z=0..3) + wlog GEMM (z=4), one launch
    bigw_kernel<<<dim3(8, 16, NZ + 1), 256, 0, stream>>>(
        vw, Wcat, parts, kr, km_bf, km_b, wlog);
    // 5. pure streaming memory pass (softmax + e/a prologue, r -> kr[:,256:])
    mem_stream_kernel<<<2 * N_, 256, 0, stream>>>(mem_in, wlog, parts, mem_out, kr);
    // 6. f GEMM fused with y reduction (f stays in registers)
    fy_kernel<<<N_ / 64, 256, 0, stream>>>(kr, sum_bf, sum_b, out_w, out_b, y_out);
}